// Round 6
// baseline (81.858 us; speedup 1.0000x reference)
//
#include <hip/hip_runtime.h>

constexpr int N = 512;    // samples
constexpr int D = 256;    // feature dim
constexpr int TILE = 32;  // gram tile
constexpr int S4 = 33;    // padded LDS row stride in float4 (128/4 + 1)
#define MARGIN 1.0f

// d_ws float layout: G0[512*512] | G1[512*512] | norms0[512] | norms1[512]
// | acc{sum, cnt, (int)done}
#define OFF_G1   (N * N)
#define OFF_N0   (2 * N * N)
#define OFF_N1   (2 * N * N + N)
#define OFF_ACC  (2 * N * N + 2 * N)

// Kernel A: G_h = X[:, h*128:(h+1)*128] @ X^T (K-split halves), plus norms
// from the diagonal tiles. 512 blocks = 16x16 tiles x 2 K-halves.
// 32x32 tile, 256 threads, 2x2 micro-tile (rows {m,m+16} x cols {n,n+16});
// LDS pad to 33 float4/row -> compute-loop reads are broadcast or 2-way (free).
__global__ __launch_bounds__(256) void gram_tile(
    const float* __restrict__ x, float* __restrict__ ws) {
  __shared__ float4 At[TILE][S4];
  __shared__ float4 Bt[TILE][S4];

  const int bid = blockIdx.x;
  const int h = bid >> 8;               // K-half
  const int tile = bid & 255;
  const int tr = tile >> 4, tc = tile & 15;
  const int t = threadIdx.x;

  float* G = ws + (size_t)h * OFF_G1;
  float* norms = ws + OFF_N0 + h * N;

  if (bid == 0 && t == 0) {             // zero kernel-B accumulators
    ws[OFF_ACC + 0] = 0.f;
    ws[OFF_ACC + 1] = 0.f;
    ((int*)ws)[OFF_ACC + 2] = 0;
  }

  // stage 32 rows x 32 float4 per tile (coalesced: wave = 2 rows x 512B)
  const float4* xv = (const float4*)x;  // row stride 64 float4
  #pragma unroll
  for (int p = 0; p < 4; ++p) {
    int f = t + p * 256;                // 0..1023
    int row = f >> 5, c4 = f & 31;
    At[row][c4] = xv[(size_t)(tr * TILE + row) * 64 + h * 32 + c4];
    Bt[row][c4] = xv[(size_t)(tc * TILE + row) * 64 + h * 32 + c4];
  }
  __syncthreads();

  const int m = t >> 4, n = t & 15;
  float a00 = 0.f, a01 = 0.f, a10 = 0.f, a11 = 0.f;
  #pragma unroll 4
  for (int k = 0; k < 32; ++k) {
    float4 r0 = At[m][k];
    float4 r1 = At[m + 16][k];
    float4 c0 = Bt[n][k];
    float4 c1 = Bt[n + 16][k];
    a00 += r0.x * c0.x + r0.y * c0.y + r0.z * c0.z + r0.w * c0.w;
    a01 += r0.x * c1.x + r0.y * c1.y + r0.z * c1.z + r0.w * c1.w;
    a10 += r1.x * c0.x + r1.y * c0.y + r1.z * c0.z + r1.w * c0.w;
    a11 += r1.x * c1.x + r1.y * c1.y + r1.z * c1.z + r1.w * c1.w;
  }

  const int gr = tr * TILE + m, gc = tc * TILE + n;
  G[(size_t)gr * N + gc]             = a00;   // wave = 4 rows x 64B: coalesced
  G[(size_t)gr * N + gc + 16]        = a01;
  G[(size_t)(gr + 16) * N + gc]      = a10;
  G[(size_t)(gr + 16) * N + gc + 16] = a11;
  if (tr == tc && m == n) {                   // diagonal -> squared norms
    norms[gr] = a00;
    norms[gr + 16] = a11;
  }
}

// Kernel B: block i builds dist row i from G0+G1+norms (2 j's per thread,
// registers only), compacts valid positives (t[j]==t[i], j!=i), sums
// relu(c_j - d_ik) over valid (j,k), reduces, atomics; last block finalizes.
__global__ __launch_bounds__(256) void triplet_rows(
    const float* __restrict__ wsc, const int* __restrict__ tgt,
    float* __restrict__ ws, float* __restrict__ out) {
  __shared__ float clist[N];
  __shared__ int nv;
  __shared__ float wred[8];

  const int i = blockIdx.x;
  const int t = threadIdx.x;
  const int ti = tgt[i];
  const float* G0 = wsc;
  const float* G1 = wsc + OFF_G1;
  const float* n0 = wsc + OFF_N0;
  const float* n1 = wsc + OFF_N1;
  float* acc = ws + OFF_ACC;

  if (t == 0) nv = 0;
  const float sqi = n0[i] + n1[i];
  const int j0 = 2 * t, j1 = 2 * t + 1;
  float2 g0 = ((const float2*)(G0 + (size_t)i * N))[t];
  float2 g1 = ((const float2*)(G1 + (size_t)i * N))[t];
  float2 q0 = ((const float2*)n0)[t];
  float2 q1 = ((const float2*)n1)[t];
  int2 tj = ((const int2*)tgt)[t];
  float d0 = sqrtf(fmaxf(sqi + q0.x + q1.x - 2.f * (g0.x + g1.x), 1e-16f));
  float d1 = sqrtf(fmaxf(sqi + q0.y + q1.y - 2.f * (g0.y + g1.y), 1e-16f));
  // k-side mask in registers (this thread owns k = j0, j1)
  float mk0 = (tj.x != ti) ? d0 : __builtin_inff();
  float mk1 = (tj.y != ti) ? d1 : __builtin_inff();
  __syncthreads();                           // nv = 0 visible
  if (tj.x == ti && j0 != i) { int s = atomicAdd(&nv, 1); clist[s] = d0 + MARGIN; }
  if (tj.y == ti && j1 != i) { int s = atomicAdd(&nv, 1); clist[s] = d1 + MARGIN; }
  __syncthreads();

  float sum = 0.f, cnt = 0.f;
  const int n = nv;
  for (int v = 0; v < n; ++v) {
    float c = clist[v];                      // LDS broadcast
    float a0 = c - mk0;
    float a1 = c - mk1;
    sum += fmaxf(a0, 0.f) + fmaxf(a1, 0.f);
    cnt += (a0 > 1e-16f ? 1.f : 0.f) + (a1 > 1e-16f ? 1.f : 0.f);
  }

  #pragma unroll
  for (int off = 32; off > 0; off >>= 1) {
    sum += __shfl_down(sum, off);
    cnt += __shfl_down(cnt, off);
  }
  const int wave = t >> 6, lane = t & 63;
  if (lane == 0) { wred[wave] = sum; wred[4 + wave] = cnt; }
  __syncthreads();
  if (t == 0) {
    atomicAdd(&acc[0], wred[0] + wred[1] + wred[2] + wred[3]);
    atomicAdd(&acc[1], wred[4] + wred[5] + wred[6] + wred[7]);
    __threadfence();
    int old = atomicAdd((int*)&acc[2], 1);
    if (old == N - 1) {                      // last block: finalize
      float s = atomicAdd(&acc[0], 0.f);     // coherent L2 read via RMW
      float c = atomicAdd(&acc[1], 0.f);
      out[0] = s / (c + 1e-16f);
    }
  }
}

extern "C" void kernel_launch(void* const* d_in, const int* in_sizes, int n_in,
                              void* d_out, int out_size, void* d_ws, size_t ws_size,
                              hipStream_t stream) {
  const float* x = (const float*)d_in[0];   // [512, 256] fp32
  const int* tgt = (const int*)d_in[1];     // [512] int32
  float* out = (float*)d_out;               // scalar fp32
  float* ws = (float*)d_ws;

  gram_tile<<<2 * 256, 256, 0, stream>>>(x, ws);
  triplet_rows<<<N, 256, 0, stream>>>(ws, tgt, ws, out);
}

// Round 7
// 67.751 us; speedup vs baseline: 1.2082x; 1.2082x over previous
//
#include <hip/hip_runtime.h>

constexpr int N = 512;   // number of samples
constexpr int D = 256;   // feature dim
#define MARGIN 1.0f

// Block i (1024 threads = 16 waves; 512 blocks -> 32 waves/CU, max occupancy):
// dist row i via d^2 = sum((a-b)^2)  (no norms, no Gram, single reduction
// variable), coalesced cooperative reads (16-lane group per row), compact
// valid positives (t[j]==t[i], j!=i), then sum relu(c_j - d_ik) over (j,k).
// Partials to d_ws; finalize kernel reduces.
__global__ __launch_bounds__(1024, 8) void triplet_fused(
    const float* __restrict__ x, const int* __restrict__ tgt,
    float* __restrict__ part) {
  __shared__ __align__(16) float m[N];      // dist row, +INF at positives
  __shared__ float clist[N];                // compacted c = d_ap + margin
  __shared__ int nv;
  __shared__ float wred[32];                // 16 waves x {sum | cnt}

  const int i = blockIdx.x;
  const int tid = threadIdx.x;              // 1024 threads = 16 waves
  const int ti = tgt[i];
  const int wave = tid >> 6, lane = tid & 63;
  const int sub = lane & 15, rg = lane >> 4; // chunk-in-row, row-in-group

  if (tid == 0) nv = 0;

  // row i fragment, loop-invariant in registers (global; L1 after 1st wave)
  const float4* xiv = (const float4*)(x + (size_t)i * D);
  float4 a0 = xiv[sub];
  float4 a1 = xiv[16 + sub];
  float4 a2 = xiv[32 + sub];
  float4 a3 = xiv[48 + sub];
  __syncthreads();                          // nv=0 visible before compaction

  // Wave w covers rows [w*32, w*32+32): 4 rows/iter (one per 16-lane group).
  // Per-block rotation decorrelates the 512 blocks' L2 streams.
  const int rot = (i * 171) & (N - 1);
  const int rbase = wave * 32 + rg;
  #pragma unroll 2
  for (int it = 0; it < 8; ++it) {
    const int r = (rbase + it * 4 + rot) & (N - 1);
    const float4* xr = (const float4*)(x + (size_t)r * D);
    float4 b0 = xr[sub];
    float4 b1 = xr[16 + sub];
    float4 b2 = xr[32 + sub];
    float4 b3 = xr[48 + sub];
    // d^2 partial: paired independent sub/fma chains (packed-fp32 friendly)
    float4 e0, e1, e2, e3;
    e0.x = a0.x - b0.x; e0.y = a0.y - b0.y; e0.z = a0.z - b0.z; e0.w = a0.w - b0.w;
    e1.x = a1.x - b1.x; e1.y = a1.y - b1.y; e1.z = a1.z - b1.z; e1.w = a1.w - b1.w;
    e2.x = a2.x - b2.x; e2.y = a2.y - b2.y; e2.z = a2.z - b2.z; e2.w = a2.w - b2.w;
    e3.x = a3.x - b3.x; e3.y = a3.y - b3.y; e3.z = a3.z - b3.z; e3.w = a3.w - b3.w;
    float s01 = e0.x*e0.x + e0.y*e0.y + e0.z*e0.z + e0.w*e0.w
              + e1.x*e1.x + e1.y*e1.y + e1.z*e1.z + e1.w*e1.w;
    float s23 = e2.x*e2.x + e2.y*e2.y + e2.z*e2.z + e2.w*e2.w
              + e3.x*e3.x + e3.y*e3.y + e3.z*e3.z + e3.w*e3.w;
    float s = s01 + s23;
    // reduce over the 16-lane group (lane sub==0 gets clean value)
    #pragma unroll
    for (int off = 8; off > 0; off >>= 1) s += __shfl_down(s, off);
    if (sub == 0) {
      float d = sqrtf(fmaxf(s, 1e-16f));
      int tj = tgt[r];
      m[r] = (tj != ti) ? d : __builtin_inff(); // +INF masks positives as k
      if (tj == ti && r != i) {
        int sl = atomicAdd(&nv, 1);             // LDS atomic, ~7 hits total
        clist[sl] = d + MARGIN;
      }
    }
  }
  __syncthreads();

  // triplet phase: thread pair (tid, tid+512) shares element e=tid&511 and
  // splits the clist between them (v = half, half+2, ...)
  float sum = 0.f, cnt = 0.f;
  const int e = tid & 511, half = tid >> 9;
  const float mk = m[e];
  const int n = nv;
  for (int v = half; v < n; v += 2) {
    float a = clist[v] - mk;                  // clist[v] is LDS broadcast
    sum += fmaxf(a, 0.f);
    cnt += (a > 1e-16f ? 1.f : 0.f);
  }

  // block reduction over 16 waves, one partial pair per block
  #pragma unroll
  for (int off = 32; off > 0; off >>= 1) {
    sum += __shfl_down(sum, off);
    cnt += __shfl_down(cnt, off);
  }
  if (lane == 0) { wred[wave] = sum; wred[16 + wave] = cnt; }
  __syncthreads();
  if (tid == 0) {
    float s = 0.f, c = 0.f;
    #pragma unroll
    for (int w = 0; w < 16; ++w) { s += wred[w]; c += wred[16 + w]; }
    part[2 * i] = s;
    part[2 * i + 1] = c;
  }
}

// Reduce 512 (sum,cnt) partials and divide.
__global__ __launch_bounds__(512) void triplet_finalize(
    const float* __restrict__ part, float* __restrict__ out) {
  __shared__ float wred[16];
  const int tid = threadIdx.x;
  float s = part[2 * tid], c = part[2 * tid + 1];
  #pragma unroll
  for (int off = 32; off > 0; off >>= 1) {
    s += __shfl_down(s, off);
    c += __shfl_down(c, off);
  }
  int wave = tid >> 6, lane = tid & 63;
  if (lane == 0) { wred[wave] = s; wred[8 + wave] = c; }
  __syncthreads();
  if (tid == 0) {
    float ts = 0.f, tc = 0.f;
    #pragma unroll
    for (int w = 0; w < 8; ++w) { ts += wred[w]; tc += wred[8 + w]; }
    out[0] = ts / (tc + 1e-16f);
  }
}

extern "C" void kernel_launch(void* const* d_in, const int* in_sizes, int n_in,
                              void* d_out, int out_size, void* d_ws, size_t ws_size,
                              hipStream_t stream) {
  const float* x = (const float*)d_in[0];   // [512, 256] fp32
  const int* tgt = (const int*)d_in[1];     // [512] int32
  float* out = (float*)d_out;               // scalar fp32
  float* part = (float*)d_ws;               // 512 x {sum, cnt} partials

  triplet_fused<<<N, 1024, 0, stream>>>(x, tgt, part);
  triplet_finalize<<<1, 512, 0, stream>>>(part, out);
}

// Round 8
// 66.494 us; speedup vs baseline: 1.2311x; 1.0189x over previous
//
#include <hip/hip_runtime.h>

constexpr int N = 512;   // number of samples
constexpr int D = 256;   // feature dim
#define MARGIN 1.0f

// Block b (1024 threads = 16 waves) owns TWO anchors i0=2b, i1=2b+1:
// each row r is loaded ONCE and used for both anchors' distances
// (d^2 = sum((a-b)^2)), halving L2/L1 traffic vs 1 anchor/block.
// 256 blocks -> 1 block/CU, 16 waves/CU; BW-bound regime, latency covered
// by 4 loads in flight x 16 waves. Then per-anchor: compact positives
// (t[j]==t[i], j!=i) and sum relu(c_j - d_ik) over valid (j,k).
#define ACC(S, A, B)                                                   \
  { float ex = A.x - B.x, ey = A.y - B.y, ez = A.z - B.z,              \
          ew = A.w - B.w;                                              \
    S += ex * ex + ey * ey + ez * ez + ew * ew; }

__global__ __launch_bounds__(1024, 4) void triplet_fused(
    const float* __restrict__ x, const int* __restrict__ tgt,
    float* __restrict__ part) {
  __shared__ __align__(16) float m0[N], m1[N];  // dist rows, +INF at positives
  __shared__ float cl0[N], cl1[N];              // compacted c = d_ap + margin
  __shared__ int nv0, nv1;
  __shared__ float wred[32];                    // 16 waves x {sum | cnt}

  const int b = blockIdx.x;
  const int i0 = 2 * b, i1 = 2 * b + 1;
  const int tid = threadIdx.x;                  // 1024 threads = 16 waves
  const int wave = tid >> 6, lane = tid & 63;
  const int sub = lane & 15, rg = lane >> 4;    // chunk-in-row, row-in-group
  const int t0 = tgt[i0], t1 = tgt[i1];

  if (tid == 0) { nv0 = 0; nv1 = 0; }

  // both anchors' row fragments, loop-invariant registers (L1-resident)
  const float4* xa = (const float4*)(x + (size_t)i0 * D);
  const float4* xc = (const float4*)(x + (size_t)i1 * D);
  float4 a0 = xa[sub], a1 = xa[16 + sub], a2 = xa[32 + sub], a3 = xa[48 + sub];
  float4 c0 = xc[sub], c1 = xc[16 + sub], c2 = xc[32 + sub], c3 = xc[48 + sub];
  __syncthreads();                              // nv zeroed

  // Wave w covers rows [w*32, w*32+32): 4 rows/iter (one per 16-lane group).
  // Per-block rotation decorrelates the blocks' L2 streams.
  const int rot = (b * 171) & (N - 1);
  const int rbase = wave * 32 + rg;
  #pragma unroll 2
  for (int it = 0; it < 8; ++it) {
    const int r = (rbase + it * 4 + rot) & (N - 1);
    const float4* xr = (const float4*)(x + (size_t)r * D);
    float4 b0 = xr[sub];
    float4 b1 = xr[16 + sub];
    float4 b2 = xr[32 + sub];
    float4 b3 = xr[48 + sub];
    float sa = 0.f, sb = 0.f;                   // d^2 partials, both anchors
    ACC(sa, a0, b0); ACC(sa, a1, b1); ACC(sa, a2, b2); ACC(sa, a3, b3);
    ACC(sb, c0, b0); ACC(sb, c1, b1); ACC(sb, c2, b2); ACC(sb, c3, b3);
    // reduce over the 16-lane group (lane sub==0 gets clean value)
    #pragma unroll
    for (int off = 8; off > 0; off >>= 1) {
      sa += __shfl_down(sa, off);
      sb += __shfl_down(sb, off);
    }
    if (sub == 0) {
      const int tj = tgt[r];
      float da = sqrtf(fmaxf(sa, 1e-16f));
      float db = sqrtf(fmaxf(sb, 1e-16f));
      m0[r] = (tj != t0) ? da : __builtin_inff();
      m1[r] = (tj != t1) ? db : __builtin_inff();
      if (tj == t0 && r != i0) { int s = atomicAdd(&nv0, 1); cl0[s] = da + MARGIN; }
      if (tj == t1 && r != i1) { int s = atomicAdd(&nv1, 1); cl1[s] = db + MARGIN; }
    }
  }
  __syncthreads();

  // triplet phase: thread pair (tid, tid+512) shares element e=tid&511 and
  // splits each clist between them (v = half, half+2, ...)
  float sum = 0.f, cnt = 0.f;
  const int e = tid & 511, half = tid >> 9;
  const float mk0 = m0[e], mk1 = m1[e];
  const int n0 = nv0, n1 = nv1;
  for (int v = half; v < n0; v += 2) {
    float a = cl0[v] - mk0;                     // cl0[v] is LDS broadcast
    sum += fmaxf(a, 0.f);
    cnt += (a > 1e-16f ? 1.f : 0.f);
  }
  for (int v = half; v < n1; v += 2) {
    float a = cl1[v] - mk1;
    sum += fmaxf(a, 0.f);
    cnt += (a > 1e-16f ? 1.f : 0.f);
  }

  // block reduction over 16 waves, one partial pair per block
  #pragma unroll
  for (int off = 32; off > 0; off >>= 1) {
    sum += __shfl_down(sum, off);
    cnt += __shfl_down(cnt, off);
  }
  if (lane == 0) { wred[wave] = sum; wred[16 + wave] = cnt; }
  __syncthreads();
  if (tid == 0) {
    float s = 0.f, c = 0.f;
    #pragma unroll
    for (int w = 0; w < 16; ++w) { s += wred[w]; c += wred[16 + w]; }
    part[2 * b] = s;
    part[2 * b + 1] = c;
  }
}

// Reduce 256 (sum,cnt) partials and divide.
__global__ __launch_bounds__(256) void triplet_finalize(
    const float* __restrict__ part, float* __restrict__ out) {
  __shared__ float wred[8];
  const int tid = threadIdx.x;
  float s = part[2 * tid], c = part[2 * tid + 1];
  #pragma unroll
  for (int off = 32; off > 0; off >>= 1) {
    s += __shfl_down(s, off);
    c += __shfl_down(c, off);
  }
  int wave = tid >> 6, lane = tid & 63;
  if (lane == 0) { wred[wave] = s; wred[4 + wave] = c; }
  __syncthreads();
  if (tid == 0) {
    float ts = wred[0] + wred[1] + wred[2] + wred[3];
    float tc = wred[4] + wred[5] + wred[6] + wred[7];
    out[0] = ts / (tc + 1e-16f);
  }
}

extern "C" void kernel_launch(void* const* d_in, const int* in_sizes, int n_in,
                              void* d_out, int out_size, void* d_ws, size_t ws_size,
                              hipStream_t stream) {
  const float* x = (const float*)d_in[0];   // [512, 256] fp32
  const int* tgt = (const int*)d_in[1];     // [512] int32
  float* out = (float*)d_out;               // scalar fp32
  float* part = (float*)d_ws;               // 256 x {sum, cnt} partials

  triplet_fused<<<N / 2, 1024, 0, stream>>>(x, tgt, part);
  triplet_finalize<<<1, 256, 0, stream>>>(part, out);
}